// Round 5
// baseline (405.477 us; speedup 1.0000x reference)
//
#include <hip/hip_runtime.h>
#include <hip/hip_fp16.h>
#include <math.h>

#define NNODES 50000
#define NEDGES 800000
#define HD     128      // H*D
#define NHEADS 4
#define DH     32

#define TILE_R 64       // gemm rows per block
#define AKPF   136      // full-K padded stride (halves)

// Bucketed CSR build (round-9 lesson: naive 4B random scatter = 17x write amp;
// all fine-grained scatter must happen in LDS).
#define NBUCK  196
#define BCAP   6144
#define P1_T   512
#define P1_EPB 4096
#define P2_T   512

#define NCHUNK 196      // smax node chunks of 256

typedef _Float16 f16x8 __attribute__((ext_vector_type(8)));
typedef float    f32x4 __attribute__((ext_vector_type(4)));

static __device__ __forceinline__ float elu(float x){ return x > 0.f ? x : __expf(x) - 1.f; }

// ---------------- fused prep: btail init + W transpose/cvt + Wproj transpose/cvt ----
__global__ void prep_kernel(const float* __restrict__ W0, const float* __restrict__ W1,
                            const float* __restrict__ W2, const float* __restrict__ Wp,
                            _Float16* __restrict__ wt, _Float16* __restrict__ wt2,
                            int* __restrict__ btail){
  int id = blockIdx.x*blockDim.x + threadIdx.x;
  if (id < NBUCK) btail[id] = id*BCAP;
  if (id < 3*16384){
    int l = id >> 14, rem = id & 16383;
    int n = rem >> 7, k = rem & 127;
    const float* W = (l==0) ? W0 : (l==1) ? W1 : W2;
    wt[(size_t)l*16384 + n*128 + k] = (_Float16)W[k*128 + n];
  } else if (id < 3*16384 + 12288){
    int rem = id - 3*16384;
    int k = rem >> 5, n = rem & 31;      // Wproj[384][32] -> wt2[32][384]
    wt2[n*384 + k] = (_Float16)Wp[k*32 + n];
  }
}

// ---------------- CSR build, bucketed ----------------

__global__ __launch_bounds__(P1_T) void p1_bucket_kernel(
    const int* __restrict__ src, const int* __restrict__ dst,
    int* __restrict__ btail, unsigned int* __restrict__ bstage, int e)
{
  __shared__ int cnt[NBUCK];
  __shared__ int gstart[NBUCK];
  int t = threadIdx.x;
  int base = blockIdx.x * P1_EPB;
  for (int i = t; i < NBUCK; i += P1_T) cnt[i] = 0;
  __syncthreads();
  int s_[8], b_[8], dl_[8];
  #pragma unroll
  for (int j = 0; j < 8; j++){
    int i = base + j*P1_T + t;
    if (i < e){
      int d = dst[i];
      s_[j]  = src[i];
      b_[j]  = d >> 8;
      dl_[j] = d & 255;
      atomicAdd(&cnt[b_[j]], 1);
    } else b_[j] = -1;
  }
  __syncthreads();
  for (int i = t; i < NBUCK; i += P1_T){
    gstart[i] = cnt[i] ? atomicAdd(&btail[i], cnt[i]) : 0;
    cnt[i] = 0;
  }
  __syncthreads();
  #pragma unroll
  for (int j = 0; j < 8; j++){
    if (b_[j] >= 0){
      int p = atomicAdd(&cnt[b_[j]], 1);
      bstage[(size_t)gstart[b_[j]] + p] = ((unsigned)dl_[j] << 16) | (unsigned)s_[j];
    }
  }
}

// p2: per-bucket counting sort -> CSR. Round-21: bucket_scan kernel folded in
// (each block redundantly scans the 196 bucket sizes in LDS — cheaper than a
// separate launch + gap).
__global__ __launch_bounds__(P2_T) void p2_csr_kernel(
    const unsigned int* __restrict__ bstage, const int* __restrict__ btail,
    int* __restrict__ rowptr, int* __restrict__ srcs)
{
  __shared__ unsigned int ebuf[BCAP];
  __shared__ unsigned short sorted[BCAP];
  __shared__ int cnt[256], ofs[256], run[256];
  __shared__ int pf[256];
  int b = blockIdx.x, t = threadIdx.x;

  if (t < 256) pf[t] = (t < NBUCK) ? (btail[t] - t*BCAP) : 0;
  for (int i = t; i < 256; i += P2_T) cnt[i] = 0;
  __syncthreads();
  for (int off = 1; off < 256; off <<= 1){
    int v = 0;
    if (t < 256 && t >= off) v = pf[t - off];
    __syncthreads();
    if (t < 256) pf[t] += v;
    __syncthreads();
  }
  int nE = btail[b] - b*BCAP;
  int gb = pf[b] - nE;                       // exclusive prefix
  if (b == 0 && t == 0) rowptr[NNODES] = pf[NBUCK-1];
  const unsigned int* bp = bstage + (size_t)b*BCAP;

  for (int i = t; i < nE; i += P2_T){
    unsigned int v = bp[i];
    ebuf[i] = v;
    atomicAdd(&cnt[v >> 16], 1);
  }
  __syncthreads();
  if (t < 256) ofs[t] = cnt[t];
  __syncthreads();
  for (int off = 1; off < 256; off <<= 1){
    int v = 0;
    if (t < 256 && t >= off) v = ofs[t - off];
    __syncthreads();
    if (t < 256) ofs[t] += v;
    __syncthreads();
  }
  if (t < 256){
    int ex = ofs[t] - cnt[t];
    run[t] = ex;
    int node = b*256 + t;
    if (node < NNODES) rowptr[node] = gb + ex;
  }
  __syncthreads();
  for (int i = t; i < nE; i += P2_T){
    unsigned int v = ebuf[i];
    int p = atomicAdd(&run[v >> 16], 1);
    sorted[p] = (unsigned short)(v & 0xFFFFu);
  }
  __syncthreads();
  for (int i = t; i < nE; i += P2_T)
    srcs[gb + i] = (int)sorted[i];
}

// ---------------- GEMM (h @ W) via MFMA fp16, full-K single-barrier staging ----------------
// Round-21: feat output and fp16 emb input are SLICE-MAJOR [8][N][16] so the
// smax gather per XCD stays inside one 1.6MB slice (L2-resident). Only the
// global addresses change; LDS layout/MFMA unchanged.
template<bool FP16IN>
__global__ __launch_bounds__(256) void gemm_feat_kernel(
    const void* __restrict__ hin, int hstride,
    const _Float16* __restrict__ Wt,   // [128 n][128 k] fp16 (pre-transposed)
    const float* __restrict__ al, const float* __restrict__ ar,
    __half* __restrict__ feat, float* __restrict__ elv, float* __restrict__ erv)
{
  __shared__ __align__(16) _Float16 Ah[TILE_R*AKPF];  // 17408 B
  __shared__ __align__(16) _Float16 Wh[HD*AKPF];      // 34816 B
  int t = threadIdx.x;
  int w = t >> 6, lane = t & 63;
  int c = lane & 15, quad = lane >> 4;
  int rbase = blockIdx.x * TILE_R;

  f32x4 acc[8];
  #pragma unroll
  for (int ct = 0; ct < 8; ct++) acc[ct] = (f32x4){0.f, 0.f, 0.f, 0.f};

  int arow = t >> 2;
  int akq  = t & 3;
  int an   = rbase + arow;
  if (FP16IN){
    // slice-major emb: row an, position kb+akq*8 -> slice (kb>>4)+(akq>>1), off (akq&1)*8
    const _Float16* base = (const _Float16*)hin;
    int off = (akq & 1) * 8;
    #pragma unroll
    for (int kb = 0; kb < HD; kb += 32){
      int sl = (kb >> 4) + (akq >> 1);
      f16x8 av = (f16x8)((_Float16)0);
      if (an < NNODES) av = *(const f16x8*)(base + (((size_t)sl*NNODES + an) << 4) + off);
      *(f16x8*)&Ah[arow*AKPF + kb + akq*8] = av;
    }
  } else {
    const float* ap = (const float*)hin + (size_t)an*hstride + akq*8;
    #pragma unroll
    for (int kb = 0; kb < HD; kb += 32){
      float4 v0 = make_float4(0.f,0.f,0.f,0.f), v1 = v0;
      if (an < NNODES){
        v0 = *(const float4*)(ap + kb);
        v1 = *(const float4*)(ap + kb + 4);
      }
      f16x8 av;
      av[0]=(_Float16)v0.x; av[1]=(_Float16)v0.y; av[2]=(_Float16)v0.z; av[3]=(_Float16)v0.w;
      av[4]=(_Float16)v1.x; av[5]=(_Float16)v1.y; av[6]=(_Float16)v1.z; av[7]=(_Float16)v1.w;
      *(f16x8*)&Ah[arow*AKPF + kb + akq*8] = av;
    }
  }
  int wn = t >> 1;
  int wk = (t & 1) * 16;
  const _Float16* wp = Wt + wn*HD + wk;
  #pragma unroll
  for (int kb = 0; kb < HD; kb += 32){
    *(uint4*)&Wh[wn*AKPF + kb + wk]     = *(const uint4*)(wp + kb);
    *(uint4*)&Wh[wn*AKPF + kb + wk + 8] = *(const uint4*)(wp + kb + 8);
  }
  __syncthreads();

  #pragma unroll
  for (int kb = 0; kb < HD; kb += 32){
    f16x8 afrag = *(const f16x8*)&Ah[(w*16 + c)*AKPF + kb + quad*8];
    #pragma unroll
    for (int ct = 0; ct < 8; ct++){
      f16x8 bfrag = *(const f16x8*)&Wh[(ct*16 + c)*AKPF + kb + quad*8];
      acc[ct] = __builtin_amdgcn_mfma_f32_16x16x32_f16(afrag, bfrag, acc[ct], 0, 0, 0);
    }
  }

  float alv[8], arv[8];
  #pragma unroll
  for (int ct = 0; ct < 8; ct++){
    int idx = (ct >> 1)*DH + (ct & 1)*16 + c;
    alv[ct] = al[idx];
    arv[ct] = ar[idx];
  }
  #pragma unroll
  for (int r = 0; r < 4; r++){
    int n = rbase + w*16 + quad*4 + r;
    float pl[4], pr[4];
    #pragma unroll
    for (int hh = 0; hh < 4; hh++){
      pl[hh] = acc[2*hh][r]*alv[2*hh] + acc[2*hh+1][r]*alv[2*hh+1];
      pr[hh] = acc[2*hh][r]*arv[2*hh] + acc[2*hh+1][r]*arv[2*hh+1];
    }
    #pragma unroll
    for (int hh = 0; hh < 4; hh++){
      pl[hh] += __shfl_xor(pl[hh], 1); pl[hh] += __shfl_xor(pl[hh], 2);
      pl[hh] += __shfl_xor(pl[hh], 4); pl[hh] += __shfl_xor(pl[hh], 8);
      pr[hh] += __shfl_xor(pr[hh], 1); pr[hh] += __shfl_xor(pr[hh], 2);
      pr[hh] += __shfl_xor(pr[hh], 4); pr[hh] += __shfl_xor(pr[hh], 8);
    }
    if (n < NNODES){
      if (c < 4){ elv[n*NHEADS + c] = pl[c]; erv[n*NHEADS + c] = pr[c]; }
      // slice-major feat: slice = ct
      #pragma unroll
      for (int ct = 0; ct < 8; ct++)
        feat[((size_t)ct*NNODES + n)*16 + c] = __float2half_rn(acc[ct][r]);
    }
  }
}

// -------- fused edge-softmax + aggregation: XCD-SLICED thread-per-node (round-21) -----
// One THREAD owns (node, 16-feature slice). slice = blockIdx.x & 7 -> blocks of
// slice s land on XCD s (round-robin dispatch heuristic); feat stored slice-major
// so XCD s's random gathers hit a 1.6MB L2-resident window instead of 12.8MB.
// 4 edges in flight (A/B batches of 2). ssum recomputed per slice (VALU is free
// here). v_fma_mix fuses f16->f32 cvt into FMA. No max subtraction (round-9).
#define MIX2(alo, ahi, pk, aa) \
  asm("v_fma_mix_f32 %0, %2, %3, %0 op_sel:[0,0,0] op_sel_hi:[1,0,0]\n\t" \
      "v_fma_mix_f32 %1, %2, %3, %1 op_sel:[1,0,0] op_sel_hi:[1,0,0]" \
      : "+v"(alo), "+v"(ahi) : "v"(pk), "v"(aa))

__global__ __launch_bounds__(256) void smax_agg_kernel(
    const int* __restrict__ rowptr, const int* __restrict__ srcs,
    const float* __restrict__ elv, const float* __restrict__ erv,
    const __half* __restrict__ feat,      // [8][N][16] slice-major
    __half* __restrict__ emb_out,         // [8][N][16] this layer
    int n)
{
  int bid  = blockIdx.x;
  int s    = bid & 7;                     // feature slice == XCD (heuristic)
  int node = (bid >> 3)*256 + threadIdx.x;
  if (node >= n) return;
  int head = s >> 1;

  int s0 = rowptr[node], s1 = rowptr[node+1];
  float erh = erv[node*4 + head];
  const __half* fbase = feat + (size_t)s*NNODES*16;

  float acc[16];
  #pragma unroll
  for (int j = 0; j < 16; j++) acc[j] = 0.f;
  float ssum = 0.f;
  const uint4 zq = make_uint4(0,0,0,0);

  int   SA[2], SB[2];
  uint4 A0[2], A1[2], B0[2], B1[2];
  float EA[2], EB[2];

#define LOADB(base_e, S, Q0, Q1, EL)                                 \
  {                                                                  \
    _Pragma("unroll")                                                \
    for (int j = 0; j < 2; j++){                                     \
      int ee = (base_e) + j;                                         \
      S[j] = (ee < s1) ? srcs[ee] : -1;                              \
    }                                                                \
    _Pragma("unroll")                                                \
    for (int j = 0; j < 2; j++){                                     \
      if (S[j] >= 0){                                                \
        const __half* fr = fbase + (size_t)S[j]*16;                  \
        Q0[j] = *(const uint4*)(fr);                                 \
        Q1[j] = *(const uint4*)(fr + 8);                             \
        EL[j] = elv[S[j]*4 + head];                                  \
      } else { Q0[j] = zq; Q1[j] = zq; EL[j] = 0.f; }                \
    }                                                                \
  }

#define ACCB(S, Q0, Q1, EL)                                          \
  {                                                                  \
    _Pragma("unroll")                                                \
    for (int j = 0; j < 2; j++){                                     \
      float x = EL[j] + erh;                                         \
      float a = (S[j] >= 0) ? __expf(fmaxf(x, 0.2f*x)) : 0.f;        \
      ssum += a;                                                     \
      MIX2(acc[0],  acc[1],  Q0[j].x, a);                            \
      MIX2(acc[2],  acc[3],  Q0[j].y, a);                            \
      MIX2(acc[4],  acc[5],  Q0[j].z, a);                            \
      MIX2(acc[6],  acc[7],  Q0[j].w, a);                            \
      MIX2(acc[8],  acc[9],  Q1[j].x, a);                            \
      MIX2(acc[10], acc[11], Q1[j].y, a);                            \
      MIX2(acc[12], acc[13], Q1[j].z, a);                            \
      MIX2(acc[14], acc[15], Q1[j].w, a);                            \
    }                                                                \
  }

  LOADB(s0, SA, A0, A1, EA);
  for (int e = s0; e < s1; e += 4){
    LOADB(e + 2, SB, B0, B1, EB);
    ACCB(SA, A0, A1, EA);
    LOADB(e + 4, SA, A0, A1, EA);
    ACCB(SB, B0, B1, EB);
  }
#undef LOADB
#undef ACCB

  // deg-0 node: ssum=0 -> inv=0 -> elu(0)=0 (matches reference zeros).
  float inv = (ssum > 0.f) ? 1.f / ssum : 0.f;
  __half2 hv[8];
  #pragma unroll
  for (int j = 0; j < 8; j++)
    hv[j] = __floats2half2_rn(elu(acc[2*j]*inv), elu(acc[2*j+1]*inv));
  __half* op = emb_out + ((size_t)s*NNODES + node)*16;
  *(uint4*)(op)     = *(uint4*)&hv[0];
  *(uint4*)(op + 8) = *(uint4*)&hv[4];
}

// ---------------- final projection via MFMA: emb @ Wproj[384,32] ----------------
// emb is [3][8][N][16] slice-major; position p in the logical 384-row maps to
// slice-array ls = p>>4, offset p&15. K=384 in-block, direct fp32 write.
__global__ __launch_bounds__(256) void proj_mfma_kernel(
    const __half* __restrict__ emb, const _Float16* __restrict__ Wt2,
    float* __restrict__ out)
{
  __shared__ __align__(16) _Float16 Ah[128*136];   // 34816 B (k-chunk of 128)
  __shared__ __align__(16) _Float16 Bh[32*392];    // 25088 B (full B)
  int t = threadIdx.x;
  int w = t >> 6, lane = t & 63;
  int c = lane & 15, quad = lane >> 4;
  int rbase = blockIdx.x * 128;

  f32x4 acc[2][2];
  #pragma unroll
  for (int rt = 0; rt < 2; rt++)
    #pragma unroll
    for (int ct = 0; ct < 2; ct++) acc[rt][ct] = (f32x4){0.f,0.f,0.f,0.f};

  // stage B once: 32 rows x 384 halves = 1536 h8-chunks, 6 per thread
  #pragma unroll
  for (int i = 0; i < 6; i++){
    int idx = i*256 + t;
    int row = idx / 48;
    int q8  = idx - row*48;
    *(f16x8*)&Bh[row*392 + q8*8] = *(const f16x8*)(Wt2 + row*384 + q8*8);
  }

  for (int kc = 0; kc < 384; kc += 128){
    // stage A chunk: 128 rows x 128 halves = 2048 h8-chunks, 8 per thread
    #pragma unroll
    for (int i = 0; i < 8; i++){
      int idx = i*256 + t;
      int row = idx >> 4;
      int q   = idx & 15;
      int gr  = rbase + row;
      int pos = kc + q*8;
      int ls  = pos >> 4;
      int off = pos & 15;
      f16x8 v = (f16x8)((_Float16)0);
      if (gr < NNODES)
        v = *(const f16x8*)((const _Float16*)emb + (((size_t)ls*NNODES + gr) << 4) + off);
      *(f16x8*)&Ah[row*136 + q*8] = v;
    }
    __syncthreads();
    #pragma unroll
    for (int kb = 0; kb < 128; kb += 32){
      #pragma unroll
      for (int rt = 0; rt < 2; rt++){
        f16x8 afrag = *(const f16x8*)&Ah[(w*32 + rt*16 + c)*136 + kb + quad*8];
        #pragma unroll
        for (int ct = 0; ct < 2; ct++){
          f16x8 bfrag = *(const f16x8*)&Bh[(ct*16 + c)*392 + kc + kb + quad*8];
          acc[rt][ct] = __builtin_amdgcn_mfma_f32_16x16x32_f16(afrag, bfrag, acc[rt][ct], 0, 0, 0);
        }
      }
    }
    __syncthreads();
  }

  #pragma unroll
  for (int rt = 0; rt < 2; rt++)
    #pragma unroll
    for (int r = 0; r < 4; r++){
      int n = rbase + w*32 + rt*16 + quad*4 + r;
      if (n < NNODES){
        out[(size_t)n*32 + c]      = acc[rt][0][r];
        out[(size_t)n*32 + 16 + c] = acc[rt][1][r];
      }
    }
}

// ---------------- launch ----------------
extern "C" void kernel_launch(void* const* d_in, const int* in_sizes, int n_in,
                              void* d_out, int out_size, void* d_ws, size_t ws_size,
                              hipStream_t stream) {
  const float* x    = (const float*)d_in[0];
  const int*   src  = (const int*)d_in[1];
  const int*   dst  = (const int*)d_in[2];
  const float* Ws_[3]  = { (const float*)d_in[3], (const float*)d_in[6], (const float*)d_in[9]  };
  const float* als[3] = { (const float*)d_in[4], (const float*)d_in[7], (const float*)d_in[10] };
  const float* ars[3] = { (const float*)d_in[5], (const float*)d_in[8], (const float*)d_in[11] };
  const float* Wproj  = (const float*)d_in[12];
  float* out = (float*)d_out;

  char* wptr = (char*)d_ws;
  auto alloc = [&](size_t bytes) -> void* {
    void* p = (void*)wptr; wptr += (bytes + 255) & ~(size_t)255; return p;
  };
  int*      btail      = (int*)     alloc((size_t)NBUCK*4);
  unsigned* bstage     = (unsigned*)alloc((size_t)NBUCK*BCAP*4);
  int*      rowptr     = (int*)     alloc((size_t)(NNODES+1)*4);
  int*      src_sorted = (int*)     alloc((size_t)NEDGES*4);
  __half*   feat       = (__half*)  alloc((size_t)8*NNODES*16*2);   // slice-major
  float*    elv        = (float*)   alloc((size_t)NNODES*NHEADS*4);
  float*    erv        = (float*)   alloc((size_t)NNODES*NHEADS*4);
  __half*   emb        = (__half*)  alloc((size_t)24*NNODES*16*2);  // [3][8][N][16]
  _Float16* wt         = (_Float16*)alloc((size_t)3*HD*HD*2);
  _Float16* wt2        = (_Float16*)alloc((size_t)32*384*2);

  // fused prep: btail init + W/Wproj transpose+fp16
  prep_kernel<<<(3*16384 + 12288 + 255)/256, 256, 0, stream>>>(
      Ws_[0], Ws_[1], Ws_[2], Wproj, wt, wt2, btail);

  // CSR build, bucketed (LDS-local scatter); scan folded into p2 (round-21)
  p1_bucket_kernel<<<(NEDGES + P1_EPB - 1)/P1_EPB, P1_T, 0, stream>>>(
      src, dst, btail, bstage, NEDGES);
  p2_csr_kernel<<<NBUCK, P2_T, 0, stream>>>(bstage, btail, rowptr, src_sorted);

  const int NGB = (NNODES + TILE_R - 1)/TILE_R;
  const int NSMB = NCHUNK * 8;              // (node-chunk, slice) blocks
  // layer 0: fp32 x input
  gemm_feat_kernel<false><<<NGB, 256, 0, stream>>>(
      (const void*)x, 128, wt, als[0], ars[0], feat, elv, erv);
  smax_agg_kernel<<<NSMB, 256, 0, stream>>>(rowptr, src_sorted, elv, erv,
                                            feat, emb, NNODES);
  // layers 1,2: slice-major fp16 emb input
  for (int l = 1; l < 3; l++){
    gemm_feat_kernel<true><<<NGB, 256, 0, stream>>>(
        (const void*)(emb + (size_t)(l-1)*8*NNODES*16), 0,
        wt + (size_t)l*HD*HD, als[l], ars[l], feat, elv, erv);
    smax_agg_kernel<<<NSMB, 256, 0, stream>>>(rowptr, src_sorted, elv, erv,
                                              feat, emb + (size_t)l*8*NNODES*16, NNODES);
  }

  // final projection (MFMA, K=384 in-block, direct write)
  proj_mfma_kernel<<<(NNODES + 127)/128, 256, 0, stream>>>(emb, wt2, out);
}

// Round 6
// 273.161 us; speedup vs baseline: 1.4844x; 1.4844x over previous
//
#include <hip/hip_runtime.h>
#include <hip/hip_fp16.h>
#include <math.h>

#define NNODES 50000
#define NEDGES 800000
#define HD     128      // H*D
#define NHEADS 4
#define DH     32

#define TILE_R 64       // gemm rows per block
#define AKPF   136      // full-K padded stride (halves)

// Bucketed CSR build (round-9 lesson: naive 4B random scatter = 17x write amp;
// all fine-grained scatter must happen in LDS).
#define NBUCK  196
#define BCAP   6144
#define P1_T   512
#define P1_EPB 4096
#define P2_T   512

typedef _Float16 f16x8 __attribute__((ext_vector_type(8)));
typedef float    f32x4 __attribute__((ext_vector_type(4)));

static __device__ __forceinline__ float elu(float x){ return x > 0.f ? x : __expf(x) - 1.f; }

// ---------------- CSR build, bucketed ----------------
// Round-22: prep launch removed. btail zeroed via hipMemsetAsync (btail now
// holds COUNTS; bstage slot = b*BCAP + count). W/Wproj transpose+fp16 folded
// into p1's 100K threads (1 element each, overlaps the edge loads).

__global__ __launch_bounds__(P1_T) void p1_bucket_kernel(
    const int* __restrict__ src, const int* __restrict__ dst,
    int* __restrict__ btail, unsigned int* __restrict__ bstage, int e,
    const float* __restrict__ W0, const float* __restrict__ W1,
    const float* __restrict__ W2, const float* __restrict__ Wp,
    _Float16* __restrict__ wt, _Float16* __restrict__ wt2)
{
  __shared__ int cnt[NBUCK];
  __shared__ int gstart[NBUCK];
  int t = threadIdx.x;
  int base = blockIdx.x * P1_EPB;

  // folded W-prep: one element per thread (61440 items < 196*512 threads)
  {
    int id = blockIdx.x*P1_T + t;
    if (id < 3*16384){
      int l = id >> 14, rem = id & 16383;
      int n = rem >> 7, k = rem & 127;
      const float* W = (l==0) ? W0 : (l==1) ? W1 : W2;
      wt[(size_t)l*16384 + n*128 + k] = (_Float16)W[k*128 + n];
    } else if (id < 3*16384 + 12288){
      int rem = id - 3*16384;
      int k = rem >> 5, n = rem & 31;      // Wproj[384][32] -> wt2[32][384]
      wt2[n*384 + k] = (_Float16)Wp[k*32 + n];
    }
  }

  for (int i = t; i < NBUCK; i += P1_T) cnt[i] = 0;
  __syncthreads();
  int s_[8], b_[8], dl_[8];
  #pragma unroll
  for (int j = 0; j < 8; j++){
    int i = base + j*P1_T + t;
    if (i < e){
      int d = dst[i];
      s_[j]  = src[i];
      b_[j]  = d >> 8;
      dl_[j] = d & 255;
      atomicAdd(&cnt[b_[j]], 1);
    } else b_[j] = -1;
  }
  __syncthreads();
  for (int i = t; i < NBUCK; i += P1_T){
    gstart[i] = (cnt[i] ? atomicAdd(&btail[i], cnt[i]) : 0) + i*BCAP;
    cnt[i] = 0;
  }
  __syncthreads();
  #pragma unroll
  for (int j = 0; j < 8; j++){
    if (b_[j] >= 0){
      int p = atomicAdd(&cnt[b_[j]], 1);
      bstage[(size_t)gstart[b_[j]] + p] = ((unsigned)dl_[j] << 16) | (unsigned)s_[j];
    }
  }
}

// p2: per-bucket counting sort -> CSR, with bucket scan folded in (round-21).
__global__ __launch_bounds__(P2_T) void p2_csr_kernel(
    const unsigned int* __restrict__ bstage, const int* __restrict__ btail,
    int* __restrict__ rowptr, int* __restrict__ srcs)
{
  __shared__ unsigned int ebuf[BCAP];
  __shared__ unsigned short sorted[BCAP];
  __shared__ int cnt[256], ofs[256], run[256];
  __shared__ int pf[256];
  int b = blockIdx.x, t = threadIdx.x;

  if (t < 256) pf[t] = (t < NBUCK) ? btail[t] : 0;      // btail = count now
  for (int i = t; i < 256; i += P2_T) cnt[i] = 0;
  __syncthreads();
  for (int off = 1; off < 256; off <<= 1){
    int v = 0;
    if (t < 256 && t >= off) v = pf[t - off];
    __syncthreads();
    if (t < 256) pf[t] += v;
    __syncthreads();
  }
  int nE = btail[b];
  int gb = pf[b] - nE;                       // exclusive prefix
  if (b == 0 && t == 0) rowptr[NNODES] = pf[NBUCK-1];
  const unsigned int* bp = bstage + (size_t)b*BCAP;

  for (int i = t; i < nE; i += P2_T){
    unsigned int v = bp[i];
    ebuf[i] = v;
    atomicAdd(&cnt[v >> 16], 1);
  }
  __syncthreads();
  if (t < 256) ofs[t] = cnt[t];
  __syncthreads();
  for (int off = 1; off < 256; off <<= 1){
    int v = 0;
    if (t < 256 && t >= off) v = ofs[t - off];
    __syncthreads();
    if (t < 256) ofs[t] += v;
    __syncthreads();
  }
  if (t < 256){
    int ex = ofs[t] - cnt[t];
    run[t] = ex;
    int node = b*256 + t;
    if (node < NNODES) rowptr[node] = gb + ex;
  }
  __syncthreads();
  for (int i = t; i < nE; i += P2_T){
    unsigned int v = ebuf[i];
    int p = atomicAdd(&run[v >> 16], 1);
    sorted[p] = (unsigned short)(v & 0xFFFFu);
  }
  __syncthreads();
  for (int i = t; i < nE; i += P2_T)
    srcs[gb + i] = (int)sorted[i];
}

// ---------------- GEMM (h @ W) via MFMA fp16, full-K single-barrier staging ----------------
// Row-major feat [N][128] and emb [N][384] (round-22 revert: slicing broke
// gather coalescing — 64 line-visits/instr, TA-bound, 2x slower).
template<bool FP16IN>
__global__ __launch_bounds__(256) void gemm_feat_kernel(
    const void* __restrict__ hin, int hstride,
    const _Float16* __restrict__ Wt,   // [128 n][128 k] fp16 (pre-transposed)
    const float* __restrict__ al, const float* __restrict__ ar,
    __half* __restrict__ feat, float* __restrict__ elv, float* __restrict__ erv)
{
  __shared__ __align__(16) _Float16 Ah[TILE_R*AKPF];  // 17408 B
  __shared__ __align__(16) _Float16 Wh[HD*AKPF];      // 34816 B
  int t = threadIdx.x;
  int w = t >> 6, lane = t & 63;
  int c = lane & 15, quad = lane >> 4;
  int rbase = blockIdx.x * TILE_R;

  f32x4 acc[8];
  #pragma unroll
  for (int ct = 0; ct < 8; ct++) acc[ct] = (f32x4){0.f, 0.f, 0.f, 0.f};

  int arow = t >> 2;
  int akq  = t & 3;
  int an   = rbase + arow;
  if (FP16IN){
    const _Float16* ap = (const _Float16*)hin + (size_t)an*hstride + akq*8;
    #pragma unroll
    for (int kb = 0; kb < HD; kb += 32){
      f16x8 av = (f16x8)((_Float16)0);
      if (an < NNODES) av = *(const f16x8*)(ap + kb);
      *(f16x8*)&Ah[arow*AKPF + kb + akq*8] = av;
    }
  } else {
    const float* ap = (const float*)hin + (size_t)an*hstride + akq*8;
    #pragma unroll
    for (int kb = 0; kb < HD; kb += 32){
      float4 v0 = make_float4(0.f,0.f,0.f,0.f), v1 = v0;
      if (an < NNODES){
        v0 = *(const float4*)(ap + kb);
        v1 = *(const float4*)(ap + kb + 4);
      }
      f16x8 av;
      av[0]=(_Float16)v0.x; av[1]=(_Float16)v0.y; av[2]=(_Float16)v0.z; av[3]=(_Float16)v0.w;
      av[4]=(_Float16)v1.x; av[5]=(_Float16)v1.y; av[6]=(_Float16)v1.z; av[7]=(_Float16)v1.w;
      *(f16x8*)&Ah[arow*AKPF + kb + akq*8] = av;
    }
  }
  int wn = t >> 1;
  int wk = (t & 1) * 16;
  const _Float16* wp = Wt + wn*HD + wk;
  #pragma unroll
  for (int kb = 0; kb < HD; kb += 32){
    *(uint4*)&Wh[wn*AKPF + kb + wk]     = *(const uint4*)(wp + kb);
    *(uint4*)&Wh[wn*AKPF + kb + wk + 8] = *(const uint4*)(wp + kb + 8);
  }
  __syncthreads();

  #pragma unroll
  for (int kb = 0; kb < HD; kb += 32){
    f16x8 afrag = *(const f16x8*)&Ah[(w*16 + c)*AKPF + kb + quad*8];
    #pragma unroll
    for (int ct = 0; ct < 8; ct++){
      f16x8 bfrag = *(const f16x8*)&Wh[(ct*16 + c)*AKPF + kb + quad*8];
      acc[ct] = __builtin_amdgcn_mfma_f32_16x16x32_f16(afrag, bfrag, acc[ct], 0, 0, 0);
    }
  }

  float alv[8], arv[8];
  #pragma unroll
  for (int ct = 0; ct < 8; ct++){
    int idx = (ct >> 1)*DH + (ct & 1)*16 + c;
    alv[ct] = al[idx];
    arv[ct] = ar[idx];
  }
  #pragma unroll
  for (int r = 0; r < 4; r++){
    int n = rbase + w*16 + quad*4 + r;
    float pl[4], pr[4];
    #pragma unroll
    for (int hh = 0; hh < 4; hh++){
      pl[hh] = acc[2*hh][r]*alv[2*hh] + acc[2*hh+1][r]*alv[2*hh+1];
      pr[hh] = acc[2*hh][r]*arv[2*hh] + acc[2*hh+1][r]*arv[2*hh+1];
    }
    #pragma unroll
    for (int hh = 0; hh < 4; hh++){
      pl[hh] += __shfl_xor(pl[hh], 1); pl[hh] += __shfl_xor(pl[hh], 2);
      pl[hh] += __shfl_xor(pl[hh], 4); pl[hh] += __shfl_xor(pl[hh], 8);
      pr[hh] += __shfl_xor(pr[hh], 1); pr[hh] += __shfl_xor(pr[hh], 2);
      pr[hh] += __shfl_xor(pr[hh], 4); pr[hh] += __shfl_xor(pr[hh], 8);
    }
    if (n < NNODES){
      if (c < 4){ elv[n*NHEADS + c] = pl[c]; erv[n*NHEADS + c] = pr[c]; }
      #pragma unroll
      for (int ct = 0; ct < 8; ct++)
        feat[(size_t)n*HD + ct*16 + c] = __float2half_rn(acc[ct][r]);
    }
  }
}

// -------- fused edge-softmax + aggregation: GROUP-OWNS-NODE + 4-deep pipeline --------
// Round-17: 8-lane group owns one node (zero cross-lane reduce; ssum replicated).
// Round-18: 4+4 A/B software pipeline (32 edges in flight per wave).
// Round-19: degree-sorting NEUTRAL. Round-21 (8-way feature slicing) REGRESSED
// 2x: slicing multiplies per-edge srcs/elv/TA cost by slice count and breaks
// 256B gather coalescing (64 line-visits/instr -> TA-bound). This group-
// cooperative 256B-row gather at ~2.3TB/s L3-random service is the floor.
#define MIX2(alo, ahi, pk, aa) \
  asm("v_fma_mix_f32 %0, %2, %3, %0 op_sel:[0,0,0] op_sel_hi:[1,0,0]\n\t" \
      "v_fma_mix_f32 %1, %2, %3, %1 op_sel:[1,0,0] op_sel_hi:[1,0,0]" \
      : "+v"(alo), "+v"(ahi) : "v"(pk), "v"(aa))

__global__ __launch_bounds__(256) void smax_agg_kernel(
    const int* __restrict__ rowptr, const int* __restrict__ srcs,
    const float* __restrict__ elv, const float* __restrict__ erv,
    const __half* __restrict__ feat, __half* __restrict__ emb_out, int n)
{
  int gid = (int)((blockIdx.x*(size_t)blockDim.x + threadIdx.x) >> 3);  // node
  if (gid >= n) return;
  int fl8  = threadIdx.x & 7;
  int fo   = fl8 * 16;          // this lane's 16-feature slice
  int head = fl8 >> 1;

  int s0 = rowptr[gid], s1 = rowptr[gid+1];
  float erh = erv[gid*4 + head];

  float acc[16];
  #pragma unroll
  for (int j = 0; j < 16; j++) acc[j] = 0.f;
  float ssum = 0.f;

  const uint4 zq = make_uint4(0,0,0,0);

  int   sA[4], sB[4];
  uint4 qA0[4], qA1[4], qB0[4], qB1[4];
  float eA[4], eB[4];

#define LOADB(base, S, Q0, Q1, EL)                                   \
  {                                                                  \
    _Pragma("unroll")                                                \
    for (int j = 0; j < 4; j++){                                     \
      int ee = (base) + j;                                           \
      S[j] = (ee < s1) ? srcs[ee] : -1;                              \
    }                                                                \
    _Pragma("unroll")                                                \
    for (int j = 0; j < 4; j++){                                     \
      if (S[j] >= 0){                                                \
        const __half* fr = feat + ((size_t)S[j] << 7) + fo;          \
        Q0[j] = *(const uint4*)(fr);                                 \
        Q1[j] = *(const uint4*)(fr + 8);                             \
        EL[j] = elv[S[j]*4 + head];                                  \
      } else { Q0[j] = zq; Q1[j] = zq; EL[j] = 0.f; }                \
    }                                                                \
  }

#define ACCB(S, Q0, Q1, EL)                                          \
  {                                                                  \
    _Pragma("unroll")                                                \
    for (int j = 0; j < 4; j++){                                     \
      float x = EL[j] + erh;                                         \
      float a = (S[j] >= 0) ? __expf(fmaxf(x, 0.2f*x)) : 0.f;        \
      ssum += a;                                                     \
      MIX2(acc[0],  acc[1],  Q0[j].x, a);                            \
      MIX2(acc[2],  acc[3],  Q0[j].y, a);                            \
      MIX2(acc[4],  acc[5],  Q0[j].z, a);                            \
      MIX2(acc[6],  acc[7],  Q0[j].w, a);                            \
      MIX2(acc[8],  acc[9],  Q1[j].x, a);                            \
      MIX2(acc[10], acc[11], Q1[j].y, a);                            \
      MIX2(acc[12], acc[13], Q1[j].z, a);                            \
      MIX2(acc[14], acc[15], Q1[j].w, a);                            \
    }                                                                \
  }

  LOADB(s0, sA, qA0, qA1, eA);
  for (int e = s0; e < s1; e += 8){
    LOADB(e + 4, sB, qB0, qB1, eB);
    ACCB(sA, qA0, qA1, eA);
    LOADB(e + 8, sA, qA0, qA1, eA);
    ACCB(sB, qB0, qB1, eB);
  }
#undef LOADB
#undef ACCB

  // ssum is identical across the group's 8 lanes: no reduction needed.
  // deg-0 node: ssum=0 -> inv=0 -> elu(0)=0 (matches reference zeros).
  float inv = (ssum > 0.f) ? 1.f / ssum : 0.f;
  __half2 hv[8];
  #pragma unroll
  for (int j = 0; j < 8; j++)
    hv[j] = __floats2half2_rn(elu(acc[2*j]*inv), elu(acc[2*j+1]*inv));
  __half* op = emb_out + (size_t)gid*384 + fo;
  *(uint4*)(op)     = *(uint4*)&hv[0];
  *(uint4*)(op + 8) = *(uint4*)&hv[4];
}

// ---------------- final projection via MFMA: emb[N,384] fp16 @ Wproj[384,32] ----------------
__global__ __launch_bounds__(256) void proj_mfma_kernel(
    const __half* __restrict__ emb, const _Float16* __restrict__ Wt2,
    float* __restrict__ out)
{
  __shared__ __align__(16) _Float16 Ah[128*136];   // 34816 B (k-chunk of 128)
  __shared__ __align__(16) _Float16 Bh[32*392];    // 25088 B (full B)
  int t = threadIdx.x;
  int w = t >> 6, lane = t & 63;
  int c = lane & 15, quad = lane >> 4;
  int rbase = blockIdx.x * 128;

  f32x4 acc[2][2];
  #pragma unroll
  for (int rt = 0; rt < 2; rt++)
    #pragma unroll
    for (int ct = 0; ct < 2; ct++) acc[rt][ct] = (f32x4){0.f,0.f,0.f,0.f};

  // stage B once: 32 rows x 384 halves = 1536 h8-chunks, 6 per thread
  #pragma unroll
  for (int i = 0; i < 6; i++){
    int idx = i*256 + t;
    int row = idx / 48;
    int q8  = idx - row*48;
    *(f16x8*)&Bh[row*392 + q8*8] = *(const f16x8*)(Wt2 + row*384 + q8*8);
  }

  for (int kc = 0; kc < 384; kc += 128){
    // stage A chunk: 128 rows x 128 halves = 2048 h8-chunks, 8 per thread
    #pragma unroll
    for (int i = 0; i < 8; i++){
      int idx = i*256 + t;
      int row = idx >> 4;
      int q   = idx & 15;
      int gr  = rbase + row;
      f16x8 v = (f16x8)((_Float16)0);
      if (gr < NNODES) v = *(const f16x8*)((const _Float16*)emb + (size_t)gr*384 + kc + q*8);
      *(f16x8*)&Ah[row*136 + q*8] = v;
    }
    __syncthreads();
    #pragma unroll
    for (int kb = 0; kb < 128; kb += 32){
      #pragma unroll
      for (int rt = 0; rt < 2; rt++){
        f16x8 afrag = *(const f16x8*)&Ah[(w*32 + rt*16 + c)*136 + kb + quad*8];
        #pragma unroll
        for (int ct = 0; ct < 2; ct++){
          f16x8 bfrag = *(const f16x8*)&Bh[(ct*16 + c)*392 + kc + kb + quad*8];
          acc[rt][ct] = __builtin_amdgcn_mfma_f32_16x16x32_f16(afrag, bfrag, acc[rt][ct], 0, 0, 0);
        }
      }
    }
    __syncthreads();
  }

  #pragma unroll
  for (int rt = 0; rt < 2; rt++)
    #pragma unroll
    for (int r = 0; r < 4; r++){
      int n = rbase + w*32 + rt*16 + quad*4 + r;
      if (n < NNODES){
        out[(size_t)n*32 + c]      = acc[rt][0][r];
        out[(size_t)n*32 + 16 + c] = acc[rt][1][r];
      }
    }
}

// ---------------- launch ----------------
extern "C" void kernel_launch(void* const* d_in, const int* in_sizes, int n_in,
                              void* d_out, int out_size, void* d_ws, size_t ws_size,
                              hipStream_t stream) {
  const float* x    = (const float*)d_in[0];
  const int*   src  = (const int*)d_in[1];
  const int*   dst  = (const int*)d_in[2];
  const float* Ws_[3]  = { (const float*)d_in[3], (const float*)d_in[6], (const float*)d_in[9]  };
  const float* als[3] = { (const float*)d_in[4], (const float*)d_in[7], (const float*)d_in[10] };
  const float* ars[3] = { (const float*)d_in[5], (const float*)d_in[8], (const float*)d_in[11] };
  const float* Wproj  = (const float*)d_in[12];
  float* out = (float*)d_out;

  char* wptr = (char*)d_ws;
  auto alloc = [&](size_t bytes) -> void* {
    void* p = (void*)wptr; wptr += (bytes + 255) & ~(size_t)255; return p;
  };
  int*      btail      = (int*)     alloc((size_t)NBUCK*4);
  unsigned* bstage     = (unsigned*)alloc((size_t)NBUCK*BCAP*4);
  int*      rowptr     = (int*)     alloc((size_t)(NNODES+1)*4);
  int*      src_sorted = (int*)     alloc((size_t)NEDGES*4);
  __half*   feat       = (__half*)  alloc((size_t)NNODES*HD*2);
  float*    elv        = (float*)   alloc((size_t)NNODES*NHEADS*4);
  float*    erv        = (float*)   alloc((size_t)NNODES*NHEADS*4);
  __half*   emb        = (__half*)  alloc((size_t)NNODES*384*2);
  _Float16* wt         = (_Float16*)alloc((size_t)3*HD*HD*2);
  _Float16* wt2        = (_Float16*)alloc((size_t)32*384*2);

  // btail = per-bucket COUNTS, zeroed without a kernel launch (graph-safe)
  hipMemsetAsync(btail, 0, (size_t)NBUCK*4, stream);

  // CSR build (W-prep folded into p1; scan folded into p2)
  p1_bucket_kernel<<<(NEDGES + P1_EPB - 1)/P1_EPB, P1_T, 0, stream>>>(
      src, dst, btail, bstage, NEDGES,
      Ws_[0], Ws_[1], Ws_[2], Wproj, wt, wt2);
  p2_csr_kernel<<<NBUCK, P2_T, 0, stream>>>(bstage, btail, rowptr, src_sorted);

  const int NGB = (NNODES + TILE_R - 1)/TILE_R;
  const int NSMB = (NNODES*8 + 255)/256;     // 8 lanes per node
  // layer 0: fp32 x input
  gemm_feat_kernel<false><<<NGB, 256, 0, stream>>>(
      (const void*)x, 128, wt, als[0], ars[0], feat, elv, erv);
  smax_agg_kernel<<<NSMB, 256, 0, stream>>>(rowptr, src_sorted, elv, erv,
                                            feat, emb, NNODES);
  // layers 1,2: fp16 emb input (previous layer's 128-wide slice)
  for (int l = 1; l < 3; l++){
    gemm_feat_kernel<true><<<NGB, 256, 0, stream>>>(
        (const void*)(emb + (size_t)(l-1)*128), 384,
        wt + (size_t)l*HD*HD, als[l], ars[l], feat, elv, erv);
    smax_agg_kernel<<<NSMB, 256, 0, stream>>>(rowptr, src_sorted, elv, erv,
                                              feat, emb + (size_t)l*128, NNODES);
  }

  // final projection (MFMA, K=384 in-block, direct write)
  proj_mfma_kernel<<<(NNODES + 127)/128, 256, 0, stream>>>(emb, wt2, out);
}

// Round 7
// 264.646 us; speedup vs baseline: 1.5321x; 1.0322x over previous
//
#include <hip/hip_runtime.h>
#include <hip/hip_fp16.h>
#include <math.h>

#define NNODES 50000
#define NEDGES 800000
#define HD     128      // H*D
#define NHEADS 4
#define DH     32

#define TILE_R 64       // gemm rows per block
#define AKPF   136      // full-K padded stride (halves)

// Bucketed CSR build (round-9 lesson: naive 4B random scatter = 17x write amp;
// all fine-grained scatter must happen in LDS).
#define NBUCK  196
#define BCAP   6144
#define P1_T   512
#define P1_EPB 4096
#define P2_T   512

typedef _Float16 f16x8 __attribute__((ext_vector_type(8)));
typedef float    f32x4 __attribute__((ext_vector_type(4)));

static __device__ __forceinline__ float elu(float x){ return x > 0.f ? x : __expf(x) - 1.f; }

// ---------------- CSR build, bucketed ----------------
// btail zeroed via hipMemsetAsync (holds COUNTS). W/Wproj transpose+fp16 folded
// into p1 (round-22).

__global__ __launch_bounds__(P1_T) void p1_bucket_kernel(
    const int* __restrict__ src, const int* __restrict__ dst,
    int* __restrict__ btail, unsigned int* __restrict__ bstage, int e,
    const float* __restrict__ W0, const float* __restrict__ W1,
    const float* __restrict__ W2, const float* __restrict__ Wp,
    _Float16* __restrict__ wt, _Float16* __restrict__ wt2)
{
  __shared__ int cnt[NBUCK];
  __shared__ int gstart[NBUCK];
  int t = threadIdx.x;
  int base = blockIdx.x * P1_EPB;

  // folded W-prep: one element per thread (61440 items < 196*512 threads)
  {
    int id = blockIdx.x*P1_T + t;
    if (id < 3*16384){
      int l = id >> 14, rem = id & 16383;
      int n = rem >> 7, k = rem & 127;
      const float* W = (l==0) ? W0 : (l==1) ? W1 : W2;
      wt[(size_t)l*16384 + n*128 + k] = (_Float16)W[k*128 + n];
    } else if (id < 3*16384 + 12288){
      int rem = id - 3*16384;
      int k = rem >> 5, n = rem & 31;      // Wproj[384][32] -> wt2[32][384]
      wt2[n*384 + k] = (_Float16)Wp[k*32 + n];
    }
  }

  for (int i = t; i < NBUCK; i += P1_T) cnt[i] = 0;
  __syncthreads();
  int s_[8], b_[8], dl_[8];
  #pragma unroll
  for (int j = 0; j < 8; j++){
    int i = base + j*P1_T + t;
    if (i < e){
      int d = dst[i];
      s_[j]  = src[i];
      b_[j]  = d >> 8;
      dl_[j] = d & 255;
      atomicAdd(&cnt[b_[j]], 1);
    } else b_[j] = -1;
  }
  __syncthreads();
  for (int i = t; i < NBUCK; i += P1_T){
    gstart[i] = (cnt[i] ? atomicAdd(&btail[i], cnt[i]) : 0) + i*BCAP;
    cnt[i] = 0;
  }
  __syncthreads();
  #pragma unroll
  for (int j = 0; j < 8; j++){
    if (b_[j] >= 0){
      int p = atomicAdd(&cnt[b_[j]], 1);
      bstage[(size_t)gstart[b_[j]] + p] = ((unsigned)dl_[j] << 16) | (unsigned)s_[j];
    }
  }
}

// p2: per-bucket counting sort -> CSR, bucket scan folded in (round-21).
// Round-23: srcs output as uint16 (node ids < 65536) — halves srcs traffic
// for the 3 smax passes.
__global__ __launch_bounds__(P2_T) void p2_csr_kernel(
    const unsigned int* __restrict__ bstage, const int* __restrict__ btail,
    int* __restrict__ rowptr, unsigned short* __restrict__ srcs)
{
  __shared__ unsigned int ebuf[BCAP];
  __shared__ unsigned short sorted[BCAP];
  __shared__ int cnt[256], ofs[256], run[256];
  __shared__ int pf[256];
  int b = blockIdx.x, t = threadIdx.x;

  if (t < 256) pf[t] = (t < NBUCK) ? btail[t] : 0;      // btail = count
  for (int i = t; i < 256; i += P2_T) cnt[i] = 0;
  __syncthreads();
  for (int off = 1; off < 256; off <<= 1){
    int v = 0;
    if (t < 256 && t >= off) v = pf[t - off];
    __syncthreads();
    if (t < 256) pf[t] += v;
    __syncthreads();
  }
  int nE = btail[b];
  int gb = pf[b] - nE;                       // exclusive prefix
  if (b == 0 && t == 0) rowptr[NNODES] = pf[NBUCK-1];
  const unsigned int* bp = bstage + (size_t)b*BCAP;

  for (int i = t; i < nE; i += P2_T){
    unsigned int v = bp[i];
    ebuf[i] = v;
    atomicAdd(&cnt[v >> 16], 1);
  }
  __syncthreads();
  if (t < 256) ofs[t] = cnt[t];
  __syncthreads();
  for (int off = 1; off < 256; off <<= 1){
    int v = 0;
    if (t < 256 && t >= off) v = ofs[t - off];
    __syncthreads();
    if (t < 256) ofs[t] += v;
    __syncthreads();
  }
  if (t < 256){
    int ex = ofs[t] - cnt[t];
    run[t] = ex;
    int node = b*256 + t;
    if (node < NNODES) rowptr[node] = gb + ex;
  }
  __syncthreads();
  for (int i = t; i < nE; i += P2_T){
    unsigned int v = ebuf[i];
    int p = atomicAdd(&run[v >> 16], 1);
    sorted[p] = (unsigned short)(v & 0xFFFFu);
  }
  __syncthreads();
  for (int i = t; i < nE; i += P2_T)
    srcs[gb + i] = sorted[i];
}

// ---------------- GEMM (h @ W) via MFMA fp16, full-K single-barrier staging ----------------
template<bool FP16IN>
__global__ __launch_bounds__(256) void gemm_feat_kernel(
    const void* __restrict__ hin, int hstride,
    const _Float16* __restrict__ Wt,   // [128 n][128 k] fp16 (pre-transposed)
    const float* __restrict__ al, const float* __restrict__ ar,
    __half* __restrict__ feat, float* __restrict__ elv, float* __restrict__ erv)
{
  __shared__ __align__(16) _Float16 Ah[TILE_R*AKPF];  // 17408 B
  __shared__ __align__(16) _Float16 Wh[HD*AKPF];      // 34816 B
  int t = threadIdx.x;
  int w = t >> 6, lane = t & 63;
  int c = lane & 15, quad = lane >> 4;
  int rbase = blockIdx.x * TILE_R;

  f32x4 acc[8];
  #pragma unroll
  for (int ct = 0; ct < 8; ct++) acc[ct] = (f32x4){0.f, 0.f, 0.f, 0.f};

  int arow = t >> 2;
  int akq  = t & 3;
  int an   = rbase + arow;
  if (FP16IN){
    const _Float16* ap = (const _Float16*)hin + (size_t)an*hstride + akq*8;
    #pragma unroll
    for (int kb = 0; kb < HD; kb += 32){
      f16x8 av = (f16x8)((_Float16)0);
      if (an < NNODES) av = *(const f16x8*)(ap + kb);
      *(f16x8*)&Ah[arow*AKPF + kb + akq*8] = av;
    }
  } else {
    const float* ap = (const float*)hin + (size_t)an*hstride + akq*8;
    #pragma unroll
    for (int kb = 0; kb < HD; kb += 32){
      float4 v0 = make_float4(0.f,0.f,0.f,0.f), v1 = v0;
      if (an < NNODES){
        v0 = *(const float4*)(ap + kb);
        v1 = *(const float4*)(ap + kb + 4);
      }
      f16x8 av;
      av[0]=(_Float16)v0.x; av[1]=(_Float16)v0.y; av[2]=(_Float16)v0.z; av[3]=(_Float16)v0.w;
      av[4]=(_Float16)v1.x; av[5]=(_Float16)v1.y; av[6]=(_Float16)v1.z; av[7]=(_Float16)v1.w;
      *(f16x8*)&Ah[arow*AKPF + kb + akq*8] = av;
    }
  }
  int wn = t >> 1;
  int wk = (t & 1) * 16;
  const _Float16* wp = Wt + wn*HD + wk;
  #pragma unroll
  for (int kb = 0; kb < HD; kb += 32){
    *(uint4*)&Wh[wn*AKPF + kb + wk]     = *(const uint4*)(wp + kb);
    *(uint4*)&Wh[wn*AKPF + kb + wk + 8] = *(const uint4*)(wp + kb + 8);
  }
  __syncthreads();

  #pragma unroll
  for (int kb = 0; kb < HD; kb += 32){
    f16x8 afrag = *(const f16x8*)&Ah[(w*16 + c)*AKPF + kb + quad*8];
    #pragma unroll
    for (int ct = 0; ct < 8; ct++){
      f16x8 bfrag = *(const f16x8*)&Wh[(ct*16 + c)*AKPF + kb + quad*8];
      acc[ct] = __builtin_amdgcn_mfma_f32_16x16x32_f16(afrag, bfrag, acc[ct], 0, 0, 0);
    }
  }

  float alv[8], arv[8];
  #pragma unroll
  for (int ct = 0; ct < 8; ct++){
    int idx = (ct >> 1)*DH + (ct & 1)*16 + c;
    alv[ct] = al[idx];
    arv[ct] = ar[idx];
  }
  #pragma unroll
  for (int r = 0; r < 4; r++){
    int n = rbase + w*16 + quad*4 + r;
    float pl[4], pr[4];
    #pragma unroll
    for (int hh = 0; hh < 4; hh++){
      pl[hh] = acc[2*hh][r]*alv[2*hh] + acc[2*hh+1][r]*alv[2*hh+1];
      pr[hh] = acc[2*hh][r]*arv[2*hh] + acc[2*hh+1][r]*arv[2*hh+1];
    }
    #pragma unroll
    for (int hh = 0; hh < 4; hh++){
      pl[hh] += __shfl_xor(pl[hh], 1); pl[hh] += __shfl_xor(pl[hh], 2);
      pl[hh] += __shfl_xor(pl[hh], 4); pl[hh] += __shfl_xor(pl[hh], 8);
      pr[hh] += __shfl_xor(pr[hh], 1); pr[hh] += __shfl_xor(pr[hh], 2);
      pr[hh] += __shfl_xor(pr[hh], 4); pr[hh] += __shfl_xor(pr[hh], 8);
    }
    if (n < NNODES){
      if (c < 4){ elv[n*NHEADS + c] = pl[c]; erv[n*NHEADS + c] = pr[c]; }
      #pragma unroll
      for (int ct = 0; ct < 8; ct++)
        feat[(size_t)n*HD + ct*16 + c] = __float2half_rn(acc[ct][r]);
    }
  }
}

// -------- fused edge-softmax + aggregation: 16-LANE GROUP-OWNS-NODE (round-23) -------
// Round-17/18: group-owns-node (no cross-lane reduce) + A/B 4-edge pipeline.
// Round-23: 16 lanes per node (16B/lane, acc[8]) doubles wave count: 12500
// waves -> full 32 waves/CU (was 24, grid-limited at 64% occupancy). Same
// 8 segments per load instruction (4 groups x 256B contiguous). This is the
// TLP disambiguation test: smax fetch (89MB) == compulsory 8-XCD broadcast
// (0.86 x 8 x 12.8MB = 88MB) so capacity tricks are dead; if latency-bound,
// +50% waves helps; if fabric-rate-bound (~2.34 TB/s), neutral -> roofline.
#define MIX2(alo, ahi, pk, aa) \
  asm("v_fma_mix_f32 %0, %2, %3, %0 op_sel:[0,0,0] op_sel_hi:[1,0,0]\n\t" \
      "v_fma_mix_f32 %1, %2, %3, %1 op_sel:[1,0,0] op_sel_hi:[1,0,0]" \
      : "+v"(alo), "+v"(ahi) : "v"(pk), "v"(aa))

__global__ __launch_bounds__(256) void smax_agg_kernel(
    const int* __restrict__ rowptr, const unsigned short* __restrict__ srcs,
    const float* __restrict__ elv, const float* __restrict__ erv,
    const __half* __restrict__ feat, __half* __restrict__ emb_out, int n)
{
  int gid = (int)((blockIdx.x*(size_t)blockDim.x + threadIdx.x) >> 4);  // node
  if (gid >= n) return;
  int fl   = threadIdx.x & 15;
  int fo   = fl * 8;            // this lane's 8-feature (16B) slice
  int head = fl >> 2;           // feature fo..fo+7 all in head fo>>5 = fl>>2

  int s0 = rowptr[gid], s1 = rowptr[gid+1];
  float erh = erv[gid*4 + head];

  float acc[8];
  #pragma unroll
  for (int j = 0; j < 8; j++) acc[j] = 0.f;
  float ssum = 0.f;

  const uint4 zq = make_uint4(0,0,0,0);

  int   sA[4], sB[4];
  uint4 qA[4], qB[4];
  float eA[4], eB[4];

#define LOADB(base, S, Q, EL)                                        \
  {                                                                  \
    _Pragma("unroll")                                                \
    for (int j = 0; j < 4; j++){                                     \
      int ee = (base) + j;                                           \
      S[j] = (ee < s1) ? (int)srcs[ee] : -1;                         \
    }                                                                \
    _Pragma("unroll")                                                \
    for (int j = 0; j < 4; j++){                                     \
      if (S[j] >= 0){                                                \
        Q[j]  = *(const uint4*)(feat + ((size_t)S[j] << 7) + fo);    \
        EL[j] = elv[S[j]*4 + head];                                  \
      } else { Q[j] = zq; EL[j] = 0.f; }                             \
    }                                                                \
  }

#define ACCB(S, Q, EL)                                               \
  {                                                                  \
    _Pragma("unroll")                                                \
    for (int j = 0; j < 4; j++){                                     \
      float x = EL[j] + erh;                                         \
      float a = (S[j] >= 0) ? __expf(fmaxf(x, 0.2f*x)) : 0.f;        \
      ssum += a;                                                     \
      MIX2(acc[0], acc[1], Q[j].x, a);                               \
      MIX2(acc[2], acc[3], Q[j].y, a);                               \
      MIX2(acc[4], acc[5], Q[j].z, a);                               \
      MIX2(acc[6], acc[7], Q[j].w, a);                               \
    }                                                                \
  }

  LOADB(s0, sA, qA, eA);
  for (int e = s0; e < s1; e += 8){
    LOADB(e + 4, sB, qB, eB);
    ACCB(sA, qA, eA);
    LOADB(e + 8, sA, qA, eA);
    ACCB(sB, qB, eB);
  }
#undef LOADB
#undef ACCB

  // ssum identical across the group's 16 lanes: no reduction.
  // deg-0 node: ssum=0 -> inv=0 -> elu(0)=0 (matches reference zeros).
  float inv = (ssum > 0.f) ? 1.f / ssum : 0.f;
  __half2 hv[4];
  #pragma unroll
  for (int j = 0; j < 4; j++)
    hv[j] = __floats2half2_rn(elu(acc[2*j]*inv), elu(acc[2*j+1]*inv));
  *(uint4*)(emb_out + (size_t)gid*384 + fo) = *(uint4*)&hv[0];
}

// ---------------- final projection via MFMA: emb[N,384] fp16 @ Wproj[384,32] ----------------
__global__ __launch_bounds__(256) void proj_mfma_kernel(
    const __half* __restrict__ emb, const _Float16* __restrict__ Wt2,
    float* __restrict__ out)
{
  __shared__ __align__(16) _Float16 Ah[128*136];   // 34816 B (k-chunk of 128)
  __shared__ __align__(16) _Float16 Bh[32*392];    // 25088 B (full B)
  int t = threadIdx.x;
  int w = t >> 6, lane = t & 63;
  int c = lane & 15, quad = lane >> 4;
  int rbase = blockIdx.x * 128;

  f32x4 acc[2][2];
  #pragma unroll
  for (int rt = 0; rt < 2; rt++)
    #pragma unroll
    for (int ct = 0; ct < 2; ct++) acc[rt][ct] = (f32x4){0.f,0.f,0.f,0.f};

  // stage B once: 32 rows x 384 halves = 1536 h8-chunks, 6 per thread
  #pragma unroll
  for (int i = 0; i < 6; i++){
    int idx = i*256 + t;
    int row = idx / 48;
    int q8  = idx - row*48;
    *(f16x8*)&Bh[row*392 + q8*8] = *(const f16x8*)(Wt2 + row*384 + q8*8);
  }

  for (int kc = 0; kc < 384; kc += 128){
    // stage A chunk: 128 rows x 128 halves = 2048 h8-chunks, 8 per thread
    #pragma unroll
    for (int i = 0; i < 8; i++){
      int idx = i*256 + t;
      int row = idx >> 4;
      int q   = idx & 15;
      int gr  = rbase + row;
      f16x8 v = (f16x8)((_Float16)0);
      if (gr < NNODES) v = *(const f16x8*)((const _Float16*)emb + (size_t)gr*384 + kc + q*8);
      *(f16x8*)&Ah[row*136 + q*8] = v;
    }
    __syncthreads();
    #pragma unroll
    for (int kb = 0; kb < 128; kb += 32){
      #pragma unroll
      for (int rt = 0; rt < 2; rt++){
        f16x8 afrag = *(const f16x8*)&Ah[(w*32 + rt*16 + c)*136 + kb + quad*8];
        #pragma unroll
        for (int ct = 0; ct < 2; ct++){
          f16x8 bfrag = *(const f16x8*)&Bh[(ct*16 + c)*392 + kc + kb + quad*8];
          acc[rt][ct] = __builtin_amdgcn_mfma_f32_16x16x32_f16(afrag, bfrag, acc[rt][ct], 0, 0, 0);
        }
      }
    }
    __syncthreads();
  }

  #pragma unroll
  for (int rt = 0; rt < 2; rt++)
    #pragma unroll
    for (int r = 0; r < 4; r++){
      int n = rbase + w*32 + rt*16 + quad*4 + r;
      if (n < NNODES){
        out[(size_t)n*32 + c]      = acc[rt][0][r];
        out[(size_t)n*32 + 16 + c] = acc[rt][1][r];
      }
    }
}

// ---------------- launch ----------------
extern "C" void kernel_launch(void* const* d_in, const int* in_sizes, int n_in,
                              void* d_out, int out_size, void* d_ws, size_t ws_size,
                              hipStream_t stream) {
  const float* x    = (const float*)d_in[0];
  const int*   src  = (const int*)d_in[1];
  const int*   dst  = (const int*)d_in[2];
  const float* Ws_[3]  = { (const float*)d_in[3], (const float*)d_in[6], (const float*)d_in[9]  };
  const float* als[3] = { (const float*)d_in[4], (const float*)d_in[7], (const float*)d_in[10] };
  const float* ars[3] = { (const float*)d_in[5], (const float*)d_in[8], (const float*)d_in[11] };
  const float* Wproj  = (const float*)d_in[12];
  float* out = (float*)d_out;

  char* wptr = (char*)d_ws;
  auto alloc = [&](size_t bytes) -> void* {
    void* p = (void*)wptr; wptr += (bytes + 255) & ~(size_t)255; return p;
  };
  int*            btail      = (int*)           alloc((size_t)NBUCK*4);
  unsigned*       bstage     = (unsigned*)      alloc((size_t)NBUCK*BCAP*4);
  int*            rowptr     = (int*)           alloc((size_t)(NNODES+1)*4);
  unsigned short* src_sorted = (unsigned short*)alloc((size_t)NEDGES*2);
  __half*         feat       = (__half*)        alloc((size_t)NNODES*HD*2);
  float*          elv        = (float*)         alloc((size_t)NNODES*NHEADS*4);
  float*          erv        = (float*)         alloc((size_t)NNODES*NHEADS*4);
  __half*         emb        = (__half*)        alloc((size_t)NNODES*384*2);
  _Float16*       wt         = (_Float16*)      alloc((size_t)3*HD*HD*2);
  _Float16*       wt2        = (_Float16*)      alloc((size_t)32*384*2);

  // btail = per-bucket COUNTS, zeroed without a kernel launch (graph-safe)
  hipMemsetAsync(btail, 0, (size_t)NBUCK*4, stream);

  // CSR build (W-prep folded into p1; scan folded into p2)
  p1_bucket_kernel<<<(NEDGES + P1_EPB - 1)/P1_EPB, P1_T, 0, stream>>>(
      src, dst, btail, bstage, NEDGES,
      Ws_[0], Ws_[1], Ws_[2], Wproj, wt, wt2);
  p2_csr_kernel<<<NBUCK, P2_T, 0, stream>>>(bstage, btail, rowptr, src_sorted);

  const int NGB = (NNODES + TILE_R - 1)/TILE_R;
  const int NSMB = (NNODES*16 + 255)/256;    // 16 lanes per node (round-23)
  // layer 0: fp32 x input
  gemm_feat_kernel<false><<<NGB, 256, 0, stream>>>(
      (const void*)x, 128, wt, als[0], ars[0], feat, elv, erv);
  smax_agg_kernel<<<NSMB, 256, 0, stream>>>(rowptr, src_sorted, elv, erv,
                                            feat, emb, NNODES);
  // layers 1,2: fp16 emb input (previous layer's 128-wide slice)
  for (int l = 1; l < 3; l++){
    gemm_feat_kernel<true><<<NGB, 256, 0, stream>>>(
        (const void*)(emb + (size_t)(l-1)*128), 384,
        wt + (size_t)l*HD*HD, als[l], ars[l], feat, elv, erv);
    smax_agg_kernel<<<NSMB, 256, 0, stream>>>(rowptr, src_sorted, elv, erv,
                                              feat, emb + (size_t)l*128, NNODES);
  }

  // final projection (MFMA, K=384 in-block, direct write)
  proj_mfma_kernel<<<(NNODES + 127)/128, 256, 0, stream>>>(emb, wt2, out);
}